// Round 4
// baseline (229.846 us; speedup 1.0000x reference)
//
#include <hip/hip_runtime.h>
#include <stdint.h>

#define H 18
#define TPB 256
#define NBLK 2048
#define DETECT_WORDS 16384

__device__ __forceinline__ void ce(unsigned long long& x, unsigned long long& y) {
    unsigned long long a = x, b = y;
    bool lt = a < b;
    x = lt ? a : b;
    y = lt ? b : a;
}

// Detect mask dtype: int32 bools -> every 32-bit word is 0 or 1.
// u8 bools -> words pack 4 bools, P(word<=1)=1/8, so over 16K words we
// see a word>1 with certainty. flag=1 -> u8 mode, flag=0 -> int32 mode.
__global__ __launch_bounds__(256) void detect_mask(const unsigned int* __restrict__ mw,
                                                   int* __restrict__ flag) {
    unsigned int acc = 0;
    for (int i = threadIdx.x; i < DETECT_WORDS; i += 256) {
        acc |= (mw[i] > 1u) ? 1u : 0u;
    }
    __shared__ int sh;
    if (threadIdx.x == 0) sh = 0;
    __syncthreads();
    if (__any(acc != 0) && (threadIdx.x & 63) == 0) atomicOr(&sh, 1);
    __syncthreads();
    if (threadIdx.x == 0) *flag = sh;
}

__global__ __launch_bounds__(TPB) void pl_main(const float* __restrict__ scores,
                                               const int* __restrict__ rankings,
                                               const unsigned char* __restrict__ mask8,
                                               const int* __restrict__ flag,
                                               int B,
                                               float* __restrict__ partial_loss,
                                               int* __restrict__ partial_cnt) {
    const bool u8mode = (*flag != 0);  // uniform across grid
    float th_loss = 0.0f;
    int th_cnt = 0;

    for (int race = blockIdx.x * TPB + threadIdx.x; race < B; race += gridDim.x * TPB) {
        const float2* s2 = reinterpret_cast<const float2*>(scores + (size_t)race * H);
        const int2*   r2 = reinterpret_cast<const int2*>(rankings + (size_t)race * H);

        int mv[H];
        if (u8mode) {
            const uchar2* m2 = reinterpret_cast<const uchar2*>(mask8 + (size_t)race * H);
#pragma unroll
            for (int q = 0; q < H / 2; ++q) {
                uchar2 t = m2[q];
                mv[2 * q]     = t.x;
                mv[2 * q + 1] = t.y;
            }
        } else {
            const int2* m2 = reinterpret_cast<const int2*>(
                reinterpret_cast<const int*>(mask8) + (size_t)race * H);
#pragma unroll
            for (int q = 0; q < H / 2; ++q) {
                int2 t = m2[q];
                mv[2 * q]     = t.x;
                mv[2 * q + 1] = t.y;
            }
        }

        float s[H];
        int key[H];
        float m = -1e30f;
        int n = 0;

#pragma unroll
        for (int q = 0; q < H / 2; ++q) {
            float2 sv = s2[q];
            int2   rv = r2[q];
            float s0 = fminf(fmaxf(sv.x, -10.0f), 10.0f);
            float s1 = fminf(fmaxf(sv.y, -10.0f), 10.0f);
            bool v0 = (mv[2 * q] != 0) && (rv.x >= 0);
            bool v1 = (mv[2 * q + 1] != 0) && (rv.y >= 0);
            s[2 * q]     = s0;
            s[2 * q + 1] = s1;
            key[2 * q]     = v0 ? (rv.x & 31) : 31;
            key[2 * q + 1] = v1 ? (rv.y & 31) : 31;
            if (v0) { n++; m = fmaxf(m, s0); }
            if (v1) { n++; m = fmaxf(m, s1); }
        }

        // pack: high 32 = (key<<5)|orig_idx (stable), low 32 = f32 bits of s
        unsigned long long a[H];
#pragma unroll
        for (int j = 0; j < H; ++j) {
            unsigned int hi = ((unsigned int)key[j] << 5) | (unsigned int)j;
            a[j] = ((unsigned long long)hi << 32) | (unsigned long long)__float_as_uint(s[j]);
        }

        // Batcher odd-even mergesort, n=18, ascending; fully unrolled -> registers
#pragma unroll
        for (int p = 1; p < H; p <<= 1) {
#pragma unroll
            for (int k = p; k >= 1; k >>= 1) {
#pragma unroll
                for (int j = k % p; j + k < H; j += 2 * k) {
#pragma unroll
                    for (int i = 0; i < k; ++i) {
                        if (i + j + k < H) {
                            if ((i + j) / (2 * p) == (i + j + k) / (2 * p)) {
                                ce(a[i + j], a[i + j + k]);
                            }
                        }
                    }
                }
            }
        }

        if (n >= 2) {
            float run = 0.0f;
            float loss = 0.0f;
            int cnt = 0;
#pragma unroll
            for (int q = H - 1; q >= 0; --q) {
                unsigned long long w = a[q];
                unsigned int hi = (unsigned int)(w >> 32);
                int kq = (int)(hi >> 5);
                if (kq < 31) {  // valid horse
                    float sv = __uint_as_float((unsigned int)w);
                    float e = __expf(sv - m);
                    run += e;
                    cnt++;
                    if (cnt > 1) {  // skip sorted position n-1 (deterministic pick)
                        float t = m + __logf(run) - sv;
                        t = fminf(fmaxf(t, 1.0000000e-8f), 18.420680744f);
                        loss += t;
                    }
                }
            }
            th_loss += loss;
            th_cnt += 1;
        }
    }

    // wave reduce (64 lanes)
#pragma unroll
    for (int off = 32; off >= 1; off >>= 1) {
        th_loss += __shfl_down(th_loss, off);
        th_cnt  += __shfl_down(th_cnt, off);
    }
    __shared__ float ls[TPB / 64];
    __shared__ int   cs[TPB / 64];
    int wid = threadIdx.x >> 6;
    int lane = threadIdx.x & 63;
    if (lane == 0) { ls[wid] = th_loss; cs[wid] = th_cnt; }
    __syncthreads();
    if (threadIdx.x == 0) {
        float L = 0.0f;
        int C = 0;
#pragma unroll
        for (int w = 0; w < TPB / 64; ++w) { L += ls[w]; C += cs[w]; }
        partial_loss[blockIdx.x] = L;
        partial_cnt[blockIdx.x]  = C;
    }
}

__global__ __launch_bounds__(1024) void pl_final(const float* __restrict__ partial_loss,
                                                 const int* __restrict__ partial_cnt,
                                                 int nb, float* __restrict__ out) {
    float L = 0.0f;
    int C = 0;
    for (int i = threadIdx.x; i < nb; i += 1024) {
        L += partial_loss[i];
        C += partial_cnt[i];
    }
#pragma unroll
    for (int off = 32; off >= 1; off >>= 1) {
        L += __shfl_down(L, off);
        C += __shfl_down(C, off);
    }
    __shared__ float ls[1024 / 64];
    __shared__ int   cs[1024 / 64];
    int wid = threadIdx.x >> 6;
    int lane = threadIdx.x & 63;
    if (lane == 0) { ls[wid] = L; cs[wid] = C; }
    __syncthreads();
    if (threadIdx.x == 0) {
        float tl = 0.0f;
        int tc = 0;
#pragma unroll
        for (int w = 0; w < 1024 / 64; ++w) { tl += ls[w]; tc += cs[w]; }
        out[0] = (tc > 0) ? (tl / (float)tc) : 0.0f;
    }
}

extern "C" void kernel_launch(void* const* d_in, const int* in_sizes, int n_in,
                              void* d_out, int out_size, void* d_ws, size_t ws_size,
                              hipStream_t stream) {
    const float*         scores   = (const float*)d_in[0];
    const int*           rankings = (const int*)d_in[1];
    const unsigned char* mask     = (const unsigned char*)d_in[2];

    int B = in_sizes[0] / H;
    int nb = (B + TPB - 1) / TPB;
    if (nb > NBLK) nb = NBLK;

    int*   flag = (int*)d_ws;
    float* pl   = (float*)((char*)d_ws + 256);
    int*   pc   = (int*)((char*)d_ws + 256 + (size_t)NBLK * sizeof(float));

    detect_mask<<<1, 256, 0, stream>>>((const unsigned int*)mask, flag);
    pl_main<<<nb, TPB, 0, stream>>>(scores, rankings, mask, flag, B, pl, pc);
    pl_final<<<1, 1024, 0, stream>>>(pl, pc, nb, (float*)d_out);
}

// Round 5
// 227.718 us; speedup vs baseline: 1.0093x; 1.0093x over previous
//
#include <hip/hip_runtime.h>
#include <stdint.h>

#define H 18
#define TPB 256
#define RPB 256  // races per block == TPB

__device__ __forceinline__ void ce(unsigned long long& x, unsigned long long& y) {
    unsigned long long a = x, b = y;
    bool lt = a < b;
    x = lt ? a : b;
    y = lt ? b : a;
}

// One block = one tile of 256 races. Staging is fully coalesced linear copy;
// key = (valid ? min(rank,30) : 31) is computed elementwise DURING staging so
// rankings/mask are read exactly once, coalesced.
__global__ __launch_bounds__(TPB) void pl_main(const float* __restrict__ scores,
                                               const int* __restrict__ rankings,
                                               const unsigned char* __restrict__ mask8,
                                               int B,
                                               float* __restrict__ partial_loss,
                                               int* __restrict__ partial_cnt) {
    __shared__ float2 sS[RPB * 9];           // 18 KB: scores, linear tile layout
    __shared__ unsigned short sK[RPB * 9];   // 4.5 KB: packed key pairs
    __shared__ int sFlag;
    __shared__ float ls[TPB / 64];
    __shared__ int   cs[TPB / 64];

    const int t = threadIdx.x;
    const int lane = t & 63;
    const int wid = t >> 6;

    // ---- mask dtype detect: int32 bools -> every word is 0/1; u8 bools pack 4
    // bools/word so P(word<=1)=1/8 -> over 256 words a >1 word appears w.p. 1.
    // First 1 KB of mask is read by every block -> L2-hot after block 0.
    if (t == 0) sFlag = 0;
    __syncthreads();
    {
        unsigned int w = reinterpret_cast<const unsigned int*>(mask8)[t];
        if (__any(w > 1u) && lane == 0) atomicOr(&sFlag, 1);
    }
    __syncthreads();
    const bool u8mode = (sFlag != 0);

    const int race0 = blockIdx.x * RPB;
    const int limit = min(RPB, B - race0);   // races in this tile
    const int nflat2 = limit * 9;            // float2 / int2 elements in tile

    const float2* s2 = reinterpret_cast<const float2*>(scores) + (size_t)race0 * 9;
    const int2*   r2 = reinterpret_cast<const int2*>(rankings) + (size_t)race0 * 9;

#pragma unroll
    for (int k = 0; k < 9; ++k) {
        int f2 = k * TPB + t;
        if (f2 < nflat2) {
            sS[f2] = s2[f2];
            int2 rv = r2[f2];
            int m0, m1;
            if (u8mode) {
                uchar2 mb = *reinterpret_cast<const uchar2*>(
                    mask8 + (size_t)race0 * 18 + 2 * (size_t)f2);
                m0 = mb.x; m1 = mb.y;
            } else {
                int2 mb = reinterpret_cast<const int2*>(mask8)[(size_t)race0 * 9 + f2];
                m0 = mb.x; m1 = mb.y;
            }
            unsigned int k0 = (m0 != 0 && rv.x >= 0) ? (unsigned int)min(rv.x, 30) : 31u;
            unsigned int k1 = (m1 != 0 && rv.y >= 0) ? (unsigned int)min(rv.y, 30) : 31u;
            sK[f2] = (unsigned short)(k0 | (k1 << 8));
        }
    }
    __syncthreads();

    float th_loss = 0.0f;
    int th_cnt = 0;

    if (t < limit) {
        unsigned long long a[H];
        float m = -1e30f;
        int n = 0;
#pragma unroll
        for (int j = 0; j < 9; ++j) {
            float2 sv = sS[t * 9 + j];
            unsigned int kp = sK[t * 9 + j];
            float s0 = fminf(fmaxf(sv.x, -10.0f), 10.0f);
            float s1 = fminf(fmaxf(sv.y, -10.0f), 10.0f);
            unsigned int k0 = kp & 0xffu;
            unsigned int k1 = (kp >> 8) & 0xffu;
            if (k0 < 31u) { n++; m = fmaxf(m, s0); }
            if (k1 < 31u) { n++; m = fmaxf(m, s1); }
            unsigned int hi0 = (k0 << 5) | (unsigned int)(2 * j);
            unsigned int hi1 = (k1 << 5) | (unsigned int)(2 * j + 1);
            a[2 * j]     = ((unsigned long long)hi0 << 32) | (unsigned long long)__float_as_uint(s0);
            a[2 * j + 1] = ((unsigned long long)hi1 << 32) | (unsigned long long)__float_as_uint(s1);
        }

        // Batcher odd-even mergesort, n=18, ascending; fully unrolled -> registers
#pragma unroll
        for (int p = 1; p < H; p <<= 1) {
#pragma unroll
            for (int k = p; k >= 1; k >>= 1) {
#pragma unroll
                for (int j = k % p; j + k < H; j += 2 * k) {
#pragma unroll
                    for (int i = 0; i < k; ++i) {
                        if (i + j + k < H) {
                            if ((i + j) / (2 * p) == (i + j + k) / (2 * p)) {
                                ce(a[i + j], a[i + j + k]);
                            }
                        }
                    }
                }
            }
        }

        if (n >= 2) {
            float run = 0.0f;
            float loss = 0.0f;
            int cnt = 0;
#pragma unroll
            for (int q = H - 1; q >= 0; --q) {
                unsigned long long w = a[q];
                unsigned int hi = (unsigned int)(w >> 32);
                int kq = (int)(hi >> 5);
                if (kq < 31) {  // valid horse
                    float sv = __uint_as_float((unsigned int)w);
                    float e = __expf(sv - m);
                    run += e;
                    cnt++;
                    if (cnt > 1) {  // skip sorted position n-1 (deterministic pick)
                        float tt = m + __logf(run) - sv;
                        tt = fminf(fmaxf(tt, 1.0000000e-8f), 18.420680744f);
                        loss += tt;
                    }
                }
            }
            th_loss = loss;
            th_cnt = 1;
        }
    }

    // wave reduce (64 lanes) then cross-wave via LDS
#pragma unroll
    for (int off = 32; off >= 1; off >>= 1) {
        th_loss += __shfl_down(th_loss, off);
        th_cnt  += __shfl_down(th_cnt, off);
    }
    if (lane == 0) { ls[wid] = th_loss; cs[wid] = th_cnt; }
    __syncthreads();
    if (t == 0) {
        float L = 0.0f;
        int C = 0;
#pragma unroll
        for (int w = 0; w < TPB / 64; ++w) { L += ls[w]; C += cs[w]; }
        partial_loss[blockIdx.x] = L;
        partial_cnt[blockIdx.x]  = C;
    }
}

__global__ __launch_bounds__(1024) void pl_final(const float* __restrict__ partial_loss,
                                                 const int* __restrict__ partial_cnt,
                                                 int nb, float* __restrict__ out) {
    float L = 0.0f;
    int C = 0;
    for (int i = threadIdx.x; i < nb; i += 1024) {
        L += partial_loss[i];
        C += partial_cnt[i];
    }
#pragma unroll
    for (int off = 32; off >= 1; off >>= 1) {
        L += __shfl_down(L, off);
        C += __shfl_down(C, off);
    }
    __shared__ float ls[1024 / 64];
    __shared__ int   cs[1024 / 64];
    int wid = threadIdx.x >> 6;
    int lane = threadIdx.x & 63;
    if (lane == 0) { ls[wid] = L; cs[wid] = C; }
    __syncthreads();
    if (threadIdx.x == 0) {
        float tl = 0.0f;
        int tc = 0;
#pragma unroll
        for (int w = 0; w < 1024 / 64; ++w) { tl += ls[w]; tc += cs[w]; }
        out[0] = (tc > 0) ? (tl / (float)tc) : 0.0f;
    }
}

extern "C" void kernel_launch(void* const* d_in, const int* in_sizes, int n_in,
                              void* d_out, int out_size, void* d_ws, size_t ws_size,
                              hipStream_t stream) {
    const float*         scores   = (const float*)d_in[0];
    const int*           rankings = (const int*)d_in[1];
    const unsigned char* mask     = (const unsigned char*)d_in[2];

    int B = in_sizes[0] / H;
    int nb = (B + RPB - 1) / RPB;  // one block per 256-race tile (3907 for B=1e6)

    float* pl = (float*)d_ws;
    int*   pc = (int*)((char*)d_ws + ((size_t)nb * sizeof(float) + 255 & ~(size_t)255));

    pl_main<<<nb, TPB, 0, stream>>>(scores, rankings, mask, B, pl, pc);
    pl_final<<<1, 1024, 0, stream>>>(pl, pc, nb, (float*)d_out);
}

// Round 8
// 225.750 us; speedup vs baseline: 1.0181x; 1.0087x over previous
//
#include <hip/hip_runtime.h>
#include <stdint.h>

#define H 18
#define TPB 256
#define RPB 256  // races per block == TPB

// One block = 256 races. No sort: rank-bucket suffix-sum algorithm.
// LDS bucket[r][t] is COLUMN-PRIVATE per thread (index always ...*RPB + t):
// no barriers needed across bucket passes, bank = t%32 -> worst 2-way (free).
__global__ __launch_bounds__(TPB) void pl_main(const float* __restrict__ scores,
                                               const int* __restrict__ rankings,
                                               const unsigned char* __restrict__ mask8,
                                               int B,
                                               float* __restrict__ partial_loss,
                                               int* __restrict__ partial_cnt) {
    __shared__ float sMem[RPB * H];          // 18 KB: staged scores, then bucket[18][256]
    __shared__ unsigned short sKp[RPB * 9];  // 4.5 KB: packed key pairs
    __shared__ int sFlag;
    __shared__ float ls[TPB / 64];
    __shared__ int   cs[TPB / 64];

    const int t = threadIdx.x;
    const int lane = t & 63;
    const int wid = t >> 6;

    // ---- mask dtype detect (proven R4/R5): int32 bools -> words are 0/1;
    // u8-packed bools -> a word >1 appears within 256 words w.p. ~1. L2-hot.
    if (t == 0) sFlag = 0;
    __syncthreads();
    {
        unsigned int w = reinterpret_cast<const unsigned int*>(mask8)[t];
        if (__any(w > 1u) && lane == 0) atomicOr(&sFlag, 1);
    }
    __syncthreads();
    const bool u8mode = (sFlag != 0);

    const int race0 = blockIdx.x * RPB;
    const int limit = min(RPB, B - race0);
    const int nflat2 = limit * 9;

    const float2* g_s2 = reinterpret_cast<const float2*>(scores) + (size_t)race0 * 9;
    const int2*   g_r2 = reinterpret_cast<const int2*>(rankings) + (size_t)race0 * 9;
    float2* sS2 = reinterpret_cast<float2*>(sMem);

    // ---- coalesced staging; key = (valid ? min(rank,30) : 31) fused in
#pragma unroll
    for (int k = 0; k < 9; ++k) {
        int f2 = k * TPB + t;
        if (f2 < nflat2) {
            sS2[f2] = g_s2[f2];
            int2 rv = g_r2[f2];
            int m0, m1;
            if (u8mode) {
                uchar2 mb = *reinterpret_cast<const uchar2*>(
                    mask8 + (size_t)race0 * 18 + 2 * (size_t)f2);
                m0 = mb.x; m1 = mb.y;
            } else {
                int2 mb = reinterpret_cast<const int2*>(mask8)[(size_t)race0 * 9 + f2];
                m0 = mb.x; m1 = mb.y;
            }
            unsigned int k0 = (m0 != 0 && rv.x >= 0) ? (unsigned int)min(rv.x, 30) : 31u;
            unsigned int k1 = (m1 != 0 && rv.y >= 0) ? (unsigned int)min(rv.y, 30) : 31u;
            sKp[f2] = (unsigned short)(k0 | (k1 << 8));
        }
    }
    __syncthreads();

    // ---- pull my race into registers (all statically indexed -> stays in VGPRs)
    float s[H];
    int key[H];
#pragma unroll
    for (int j = 0; j < H; ++j) key[j] = 31;
    float m = -1e30f;
    int n = 0;
    if (t < limit) {
#pragma unroll
        for (int j = 0; j < 9; ++j) {
            float2 sv = sS2[t * 9 + j];
            unsigned int kp = sKp[t * 9 + j];
            float s0 = fminf(fmaxf(sv.x, -10.0f), 10.0f);
            float s1 = fminf(fmaxf(sv.y, -10.0f), 10.0f);
            int k0 = (int)(kp & 0xffu);
            int k1 = (int)(kp >> 8);
            s[2 * j] = s0; s[2 * j + 1] = s1;
            key[2 * j] = k0; key[2 * j + 1] = k1;
            if (k0 < 31) { n++; m = fmaxf(m, s0); }
            if (k1 < 31) { n++; m = fmaxf(m, s1); }
        }
    }
    __syncthreads();  // staged tile fully consumed; sMem becomes bucket[18][256]

    // ---- zero my bucket column (static offsets; column-private hereafter)
#pragma unroll
    for (int r = 0; r < H; ++r) sMem[r * RPB + t] = 0.0f;

    // ---- pass B: bucket[k] += exp(s - m)  (dynamic k -> LDS, not registers)
#pragma unroll
    for (int j = 0; j < H; ++j) {
        if (key[j] < 31) {
            int a = key[j] * RPB + t;
            sMem[a] += __expf(s[j] - m);
        }
    }

    // ---- pass C: in-place suffix sums: bucket[r] = sum_{r'>=r} bucket[r']
    {
        float acc = 0.0f;
#pragma unroll
        for (int r = H - 1; r >= 0; --r) {
            acc += sMem[r * RPB + t];
            sMem[r * RPB + t] = acc;
        }
    }

    // ---- pass D: forward over idx; run_j = bucket[k_j]; then decrement.
    // Decrement removes this horse so later same-rank (larger idx) horses see
    // the correct (rank, idx)-suffix. Last valid pick = max (rank, idx):
    // tracked via key[j] >= bk in forward order; its term subtracted.
    float th_loss = 0.0f;
    int th_cnt = 0;
    {
        float loss = 0.0f, last_term = 0.0f;
        int bk = -1;
#pragma unroll
        for (int j = 0; j < H; ++j) {
            if (key[j] < 31) {
                int a = key[j] * RPB + t;
                float run = sMem[a];
                float e = __expf(s[j] - m);
                sMem[a] = run - e;
                float term = m + __logf(run) - s[j];
                term = fminf(fmaxf(term, 1.0000000e-8f), 18.420680744f);
                loss += term;
                if (key[j] >= bk) { bk = key[j]; last_term = term; }
            }
        }
        if (n >= 2) { th_loss = loss - last_term; th_cnt = 1; }
    }

    // ---- block reduce
#pragma unroll
    for (int off = 32; off >= 1; off >>= 1) {
        th_loss += __shfl_down(th_loss, off);
        th_cnt  += __shfl_down(th_cnt, off);
    }
    if (lane == 0) { ls[wid] = th_loss; cs[wid] = th_cnt; }
    __syncthreads();
    if (t == 0) {
        float L = 0.0f; int C = 0;
#pragma unroll
        for (int w = 0; w < TPB / 64; ++w) { L += ls[w]; C += cs[w]; }
        partial_loss[blockIdx.x] = L;
        partial_cnt[blockIdx.x]  = C;
    }
}

__global__ __launch_bounds__(1024) void pl_final(const float* __restrict__ partial_loss,
                                                 const int* __restrict__ partial_cnt,
                                                 int nb, float* __restrict__ out) {
    float L = 0.0f;
    int C = 0;
    for (int i = threadIdx.x; i < nb; i += 1024) {
        L += partial_loss[i];
        C += partial_cnt[i];
    }
#pragma unroll
    for (int off = 32; off >= 1; off >>= 1) {
        L += __shfl_down(L, off);
        C += __shfl_down(C, off);
    }
    __shared__ float ls[1024 / 64];
    __shared__ int   cs[1024 / 64];
    int wid = threadIdx.x >> 6;
    int lane = threadIdx.x & 63;
    if (lane == 0) { ls[wid] = L; cs[wid] = C; }
    __syncthreads();
    if (threadIdx.x == 0) {
        float tl = 0.0f;
        int tc = 0;
#pragma unroll
        for (int w = 0; w < 1024 / 64; ++w) { tl += ls[w]; tc += cs[w]; }
        out[0] = (tc > 0) ? (tl / (float)tc) : 0.0f;
    }
}

extern "C" void kernel_launch(void* const* d_in, const int* in_sizes, int n_in,
                              void* d_out, int out_size, void* d_ws, size_t ws_size,
                              hipStream_t stream) {
    const float*         scores   = (const float*)d_in[0];
    const int*           rankings = (const int*)d_in[1];
    const unsigned char* mask     = (const unsigned char*)d_in[2];

    int B = in_sizes[0] / H;
    int nb = (B + RPB - 1) / RPB;  // 3907 blocks for B=1e6

    float* pl = (float*)d_ws;
    int*   pc = (int*)((char*)d_ws + (((size_t)nb * sizeof(float) + 255) & ~(size_t)255));

    pl_main<<<nb, TPB, 0, stream>>>(scores, rankings, mask, B, pl, pc);
    pl_final<<<1, 1024, 0, stream>>>(pl, pc, nb, (float*)d_out);
}

// Round 9
// 213.019 us; speedup vs baseline: 1.0790x; 1.0598x over previous
//
#include <hip/hip_runtime.h>
#include <stdint.h>

#define H 18
#define TPB 256
#define RPB 256  // races per block == TPB

// R9: branchless pairwise Plackett-Luce. LDS used ONLY for coalesced
// staging (read-only after barrier -> no aliasing, compiler may re-read).
// Compute phase is pure-register VALU: 153 unordered-pair compare/selects
// give run_j = sum of e over (rank,idx)-suffix; no sort, no buckets, no
// divergent branches, no LDS RMW latency chains (the R8 bottleneck).
__global__ __launch_bounds__(TPB) void pl_main(const float* __restrict__ scores,
                                               const int* __restrict__ rankings,
                                               const unsigned char* __restrict__ mask8,
                                               int B,
                                               float* __restrict__ partial_loss,
                                               int* __restrict__ partial_cnt) {
    __shared__ float2 sS2[RPB * 9];          // 18 KB staged scores
    __shared__ unsigned short sKp[RPB * 9];  // 4.5 KB packed key pairs
    __shared__ int sFlag;
    __shared__ float ls[TPB / 64];
    __shared__ int   cs[TPB / 64];

    const int t = threadIdx.x;
    const int lane = t & 63;
    const int wid = t >> 6;

    // ---- mask dtype detect (proven R4-R8): int32 bools -> words 0/1;
    // u8-packed bools -> word >1 appears within 256 words w.p. ~1. L2-hot.
    if (t == 0) sFlag = 0;
    __syncthreads();
    {
        unsigned int w = reinterpret_cast<const unsigned int*>(mask8)[t];
        if (__any(w > 1u) && lane == 0) atomicOr(&sFlag, 1);
    }
    __syncthreads();
    const bool u8mode = (sFlag != 0);

    const int race0 = blockIdx.x * RPB;
    const int limit = min(RPB, B - race0);
    const int nflat2 = limit * 9;

    const float2* g_s2 = reinterpret_cast<const float2*>(scores) + (size_t)race0 * 9;
    const int2*   g_r2 = reinterpret_cast<const int2*>(rankings) + (size_t)race0 * 9;

    // ---- coalesced staging; key = (valid ? rank : 31) fused in.
    // Wave-uniform branch: only the last block takes the guarded path.
    if (blockIdx.x + 1 != (int)gridDim.x) {
        if (u8mode) {
#pragma unroll
            for (int k = 0; k < 9; ++k) {
                int f2 = k * TPB + t;
                sS2[f2] = g_s2[f2];
                int2 rv = g_r2[f2];
                uchar2 mb = *reinterpret_cast<const uchar2*>(
                    mask8 + (size_t)race0 * 18 + 2 * (size_t)f2);
                unsigned int k0 = (mb.x != 0 && rv.x >= 0) ? (unsigned int)min(rv.x, 30) : 31u;
                unsigned int k1 = (mb.y != 0 && rv.y >= 0) ? (unsigned int)min(rv.y, 30) : 31u;
                sKp[f2] = (unsigned short)(k0 | (k1 << 8));
            }
        } else {
#pragma unroll
            for (int k = 0; k < 9; ++k) {
                int f2 = k * TPB + t;
                sS2[f2] = g_s2[f2];
                int2 rv = g_r2[f2];
                int2 mb = reinterpret_cast<const int2*>(mask8)[(size_t)race0 * 9 + f2];
                unsigned int k0 = (mb.x != 0 && rv.x >= 0) ? (unsigned int)min(rv.x, 30) : 31u;
                unsigned int k1 = (mb.y != 0 && rv.y >= 0) ? (unsigned int)min(rv.y, 30) : 31u;
                sKp[f2] = (unsigned short)(k0 | (k1 << 8));
            }
        }
    } else {
#pragma unroll
        for (int k = 0; k < 9; ++k) {
            int f2 = k * TPB + t;
            if (f2 < nflat2) {
                sS2[f2] = g_s2[f2];
                int2 rv = g_r2[f2];
                int m0, m1;
                if (u8mode) {
                    uchar2 mb = *reinterpret_cast<const uchar2*>(
                        mask8 + (size_t)race0 * 18 + 2 * (size_t)f2);
                    m0 = mb.x; m1 = mb.y;
                } else {
                    int2 mb = reinterpret_cast<const int2*>(mask8)[(size_t)race0 * 9 + f2];
                    m0 = mb.x; m1 = mb.y;
                }
                unsigned int k0 = (m0 != 0 && rv.x >= 0) ? (unsigned int)min(rv.x, 30) : 31u;
                unsigned int k1 = (m1 != 0 && rv.y >= 0) ? (unsigned int)min(rv.y, 30) : 31u;
                sKp[f2] = (unsigned short)(k0 | (k1 << 8));
            }
        }
    }
    __syncthreads();

    // ---- pull my race into registers, branchless
    float s[H];
    int ck[H];          // (key<<5)|idx : lexicographic (rank, idx); valid iff < 992
    float m = -1e30f;
    int n = 0;
    if (t < limit) {
#pragma unroll
        for (int j = 0; j < 9; ++j) {
            float2 sv = sS2[t * 9 + j];
            unsigned int kp = sKp[t * 9 + j];
            float s0 = fminf(fmaxf(sv.x, -10.0f), 10.0f);
            float s1 = fminf(fmaxf(sv.y, -10.0f), 10.0f);
            int k0 = (int)(kp & 0xffu);
            int k1 = (int)(kp >> 8);
            s[2 * j] = s0; s[2 * j + 1] = s1;
            ck[2 * j]     = (k0 << 5) | (2 * j);
            ck[2 * j + 1] = (k1 << 5) | (2 * j + 1);
            bool v0 = k0 < 31, v1 = k1 < 31;
            m = fmaxf(m, v0 ? s0 : -1e30f);
            m = fmaxf(m, v1 ? s1 : -1e30f);
            n += (v0 ? 1 : 0) + (v1 ? 1 : 0);
        }
    } else {
#pragma unroll
        for (int j = 0; j < H; ++j) { s[j] = 0.0f; ck[j] = (31 << 5) | j; }
    }

    // ---- e_j = valid ? exp(s_j - m) : 0   (cndmask discards the Inf arm)
    float e[H];
#pragma unroll
    for (int j = 0; j < H; ++j) {
        e[j] = (ck[j] < (31 << 5)) ? __expf(s[j] - m) : 0.0f;
    }

    // ---- pairwise suffix sums: run_a = sum_{b: ck_b >= ck_a} e_b
    // (ck are distinct by construction: idx in low 5 bits). 153 pairs,
    // each: 1 cmp + 2 cndmask + 2 add, all static indices -> registers.
    float run[H];
#pragma unroll
    for (int a = 0; a < H; ++a) run[a] = e[a];
#pragma unroll
    for (int a = 0; a < H; ++a) {
#pragma unroll
        for (int b = a + 1; b < H; ++b) {
            bool cc = ck[b] > ck[a];
            run[a] += cc ? e[b] : 0.0f;
            run[b] += cc ? 0.0f : e[a];
        }
    }

    // ---- terms; last pick (max ck among valid) excluded; all branchless
    float loss = 0.0f, last_term = 0.0f;
    int best = -1;
#pragma unroll
    for (int j = 0; j < H; ++j) {
        float term = m + __logf(run[j]) - s[j];
        term = fminf(fmaxf(term, 1.0000000e-8f), 18.420680744f);
        bool v = ck[j] < (31 << 5);
        loss += v ? term : 0.0f;
        int ckv = v ? ck[j] : -1;
        bool up = ckv > best;
        best = up ? ckv : best;
        last_term = up ? term : last_term;
    }
    float th_loss = (n >= 2) ? (loss - last_term) : 0.0f;
    int th_cnt = (n >= 2) ? 1 : 0;

    // ---- block reduce
#pragma unroll
    for (int off = 32; off >= 1; off >>= 1) {
        th_loss += __shfl_down(th_loss, off);
        th_cnt  += __shfl_down(th_cnt, off);
    }
    if (lane == 0) { ls[wid] = th_loss; cs[wid] = th_cnt; }
    __syncthreads();
    if (t == 0) {
        float L = 0.0f; int C = 0;
#pragma unroll
        for (int w = 0; w < TPB / 64; ++w) { L += ls[w]; C += cs[w]; }
        partial_loss[blockIdx.x] = L;
        partial_cnt[blockIdx.x]  = C;
    }
}

__global__ __launch_bounds__(1024) void pl_final(const float* __restrict__ partial_loss,
                                                 const int* __restrict__ partial_cnt,
                                                 int nb, float* __restrict__ out) {
    float L = 0.0f;
    int C = 0;
    for (int i = threadIdx.x; i < nb; i += 1024) {
        L += partial_loss[i];
        C += partial_cnt[i];
    }
#pragma unroll
    for (int off = 32; off >= 1; off >>= 1) {
        L += __shfl_down(L, off);
        C += __shfl_down(C, off);
    }
    __shared__ float ls[1024 / 64];
    __shared__ int   cs[1024 / 64];
    int wid = threadIdx.x >> 6;
    int lane = threadIdx.x & 63;
    if (lane == 0) { ls[wid] = L; cs[wid] = C; }
    __syncthreads();
    if (threadIdx.x == 0) {
        float tl = 0.0f;
        int tc = 0;
#pragma unroll
        for (int w = 0; w < 1024 / 64; ++w) { tl += ls[w]; tc += cs[w]; }
        out[0] = (tc > 0) ? (tl / (float)tc) : 0.0f;
    }
}

extern "C" void kernel_launch(void* const* d_in, const int* in_sizes, int n_in,
                              void* d_out, int out_size, void* d_ws, size_t ws_size,
                              hipStream_t stream) {
    const float*         scores   = (const float*)d_in[0];
    const int*           rankings = (const int*)d_in[1];
    const unsigned char* mask     = (const unsigned char*)d_in[2];

    int B = in_sizes[0] / H;
    int nb = (B + RPB - 1) / RPB;  // 3907 blocks for B=1e6

    float* pl = (float*)d_ws;
    int*   pc = (int*)((char*)d_ws + (((size_t)nb * sizeof(float) + 255) & ~(size_t)255));

    pl_main<<<nb, TPB, 0, stream>>>(scores, rankings, mask, B, pl, pc);
    pl_final<<<1, 1024, 0, stream>>>(pl, pc, nb, (float*)d_out);
}